// Round 2
// baseline (1013.941 us; speedup 1.0000x reference)
//
#include <hip/hip_runtime.h>

// Problem constants (from reference config)
#define BATCH 4
#define NCAM  6
#define DNUM  41
#define FHN   8
#define FWN   22
#define CCH   128
#define NXV   200
#define NYV   200
#define NPTS  173184  // BATCH*NCAM*DNUM*FHN*FWN

struct Mats {
    float iR[9];    // inv(post_rots), fp32 LU (gesv-style)
    float comb[9];  // rots @ inv(intrins), fp32 no-FMA matmul
    float tr[3];    // trans
    float pt[3];    // post_trans
};

// fp32 3x3 inverse mimicking numpy's linalg.inv -> LAPACK sgesv:
//  - sgetrf (getf2): partial pivot, scale column by RECIPROCAL of pivot
//    (LAPACK sscal(1/ajj) / OpenBLAS scal alpha=1/pivot), plain mul-sub
//    rank-1 trailing update.
//  - sgetrs: row pivots on b, unit-lower forward solve (k ascending),
//    upper backward solve (k descending) with reciprocal-multiply on the
//    diagonal (OpenBLAS trsm INV() semantics).
// All fp32, no FMA contraction.
__device__ void inv3x3_f32_gesv(const float* __restrict__ Ain, float* __restrict__ inv) {
#pragma clang fp contract(off)
    float A[9];
    for (int k = 0; k < 9; ++k) A[k] = Ain[k];
    int piv[3];
    for (int j = 0; j < 3; ++j) {
        int p = j;
        float amax = fabsf(A[j * 3 + j]);
        for (int i = j + 1; i < 3; ++i) {
            float v = fabsf(A[i * 3 + j]);
            if (v > amax) { amax = v; p = i; }
        }
        piv[j] = p;
        if (p != j)
            for (int k = 0; k < 3; ++k) { float t = A[j*3+k]; A[j*3+k] = A[p*3+k]; A[p*3+k] = t; }
        float rd = 1.0f / A[j * 3 + j];
        for (int i = j + 1; i < 3; ++i) A[i * 3 + j] = A[i * 3 + j] * rd;
        for (int i = j + 1; i < 3; ++i)
            for (int k = j + 1; k < 3; ++k)
                A[i * 3 + k] = A[i * 3 + k] - A[i * 3 + j] * A[j * 3 + k];
    }
    float rdiag[3] = {1.0f / A[0], 1.0f / A[4], 1.0f / A[8]};
    for (int c = 0; c < 3; ++c) {
        float b[3] = {0.0f, 0.0f, 0.0f};
        b[c] = 1.0f;
        for (int j = 0; j < 3; ++j) { int p = piv[j]; if (p != j) { float t = b[j]; b[j] = b[p]; b[p] = t; } }
        // forward: L (unit diag), k ascending
        for (int k = 0; k < 3; ++k)
            for (int i = k + 1; i < 3; ++i)
                b[i] = b[i] - A[i * 3 + k] * b[k];
        // backward: U, k descending, reciprocal-multiply
        for (int k = 2; k >= 0; --k) {
            b[k] = b[k] * rdiag[k];
            for (int i = 0; i < k; ++i)
                b[i] = b[i] - A[i * 3 + k] * b[k];
        }
        inv[0 + c] = b[0];
        inv[3 + c] = b[1];
        inv[6 + c] = b[2];
    }
}

__global__ void prep_kernel(const float* __restrict__ rots,
                            const float* __restrict__ trans,
                            const float* __restrict__ intrins,
                            const float* __restrict__ post_rots,
                            const float* __restrict__ post_trans,
                            Mats* __restrict__ mats) {
    int i = threadIdx.x;
    if (i >= BATCH * NCAM) return;
    Mats m;
    inv3x3_f32_gesv(post_rots + i * 9, m.iR);
    float invK[9];
    inv3x3_f32_gesv(intrins + i * 9, invK);
    // combine = rots @ invK, plain fp32 mul+add (no contraction), k ascending
    {
#pragma clang fp contract(off)
        for (int r = 0; r < 3; ++r)
            for (int c = 0; c < 3; ++c) {
                float s = rots[i * 9 + r * 3 + 0] * invK[0 * 3 + c];
                s = s + rots[i * 9 + r * 3 + 1] * invK[1 * 3 + c];
                s = s + rots[i * 9 + r * 3 + 2] * invK[2 * 3 + c];
                m.comb[r * 3 + c] = s;
            }
    }
    for (int k = 0; k < 3; ++k) {
        m.tr[k] = trans[i * 3 + k];
        m.pt[k] = post_trans[i * 3 + k];
    }
    mats[i] = m;
}

__global__ __launch_bounds__(128) void scatter_kernel(const float* __restrict__ feats,
                                                      const Mats* __restrict__ mats,
                                                      float* __restrict__ out) {
#pragma clang fp contract(off)
    int p = blockIdx.x;
    // p = ((((b*NCAM + n)*DNUM + d)*FHN + h)*FWN + w)
    int w = p % FWN;
    int t = p / FWN;
    int h = t % FHN;
    t /= FHN;
    int d = t % DNUM;
    t /= DNUM;
    int n = t % NCAM;
    int b = t / NCAM;

    const Mats m = mats[b * NCAM + n];

    // frustum coords: numpy float64 linspace rounded to fp32
    float u   = (float)((double)w * (351.0 / 21.0)); // linspace(0,351,22)
    float v   = (float)((double)h * (127.0 / 7.0));  // linspace(0,127,8)
    float dep = 4.0f + (float)d;                     // arange(4,45,1)

    // pts = frustum - post_trans
    float p0 = u - m.pt[0];
    float p1 = v - m.pt[1];
    float p2 = dep - m.pt[2];
    // pts = inv(post_rots) @ pts   (ordered mul+add, no fma, j ascending)
    float q0 = m.iR[0] * p0; q0 = q0 + m.iR[1] * p1; q0 = q0 + m.iR[2] * p2;
    float q1 = m.iR[3] * p0; q1 = q1 + m.iR[4] * p1; q1 = q1 + m.iR[5] * p2;
    float q2 = m.iR[6] * p0; q2 = q2 + m.iR[7] * p1; q2 = q2 + m.iR[8] * p2;
    // un-project: (x*z, y*z, z)
    float r0 = q0 * q2;
    float r1 = q1 * q2;
    // pts = combine @ pts + trans
    float e0 = m.comb[0] * r0; e0 = e0 + m.comb[1] * r1; e0 = e0 + m.comb[2] * q2; e0 = e0 + m.tr[0];
    float e1 = m.comb[3] * r0; e1 = e1 + m.comb[4] * r1; e1 = e1 + m.comb[5] * q2; e1 = e1 + m.tr[1];
    float e2 = m.comb[6] * r0; e2 = e2 + m.comb[7] * r1; e2 = e2 + m.comb[8] * q2; e2 = e2 + m.tr[2];

    // voxel index: ((pts - (bx - dx/2)) / dx).astype(int32)  -- trunc toward zero
    float gxf = (e0 + 50.0f) / 0.5f;
    float gyf = (e1 + 50.0f) / 0.5f;
    float gzf = (e2 + 10.0f) / 20.0f;
    int gx = (int)gxf;
    int gy = (int)gyf;
    int gz = (int)gzf;
    if (gx < 0 || gx >= NXV || gy < 0 || gy >= NYV || gz < 0 || gz >= 1) return;

    int c = threadIdx.x;
    float f = feats[(size_t)p * CCH + c];
    // out[b][c][gx][gy], NZ=1
    size_t oidx = ((size_t)(b * CCH + c)) * (NXV * NYV) + (size_t)(gx * NYV + gy);
    atomicAdd(out + oidx, f);
}

extern "C" void kernel_launch(void* const* d_in, const int* in_sizes, int n_in,
                              void* d_out, int out_size, void* d_ws, size_t ws_size,
                              hipStream_t stream) {
    const float* cam_feats  = (const float*)d_in[0];
    const float* rots       = (const float*)d_in[1];
    const float* trans      = (const float*)d_in[2];
    const float* intrins    = (const float*)d_in[3];
    const float* post_rots  = (const float*)d_in[4];
    const float* post_trans = (const float*)d_in[5];
    float* out = (float*)d_out;
    Mats* mats = (Mats*)d_ws;

    prep_kernel<<<1, 64, 0, stream>>>(rots, trans, intrins, post_rots, post_trans, mats);
    hipMemsetAsync(d_out, 0, (size_t)out_size * sizeof(float), stream);
    scatter_kernel<<<NPTS, CCH, 0, stream>>>(cam_feats, mats, out);
}

// Round 3
// 231.211 us; speedup vs baseline: 4.3854x; 4.3854x over previous
//
#include <hip/hip_runtime.h>

// Problem constants (from reference config)
#define BATCH 4
#define NCAM  6
#define DNUM  41
#define FHN   8
#define FWN   22
#define CCH   128
#define NXV   200
#define NYV   200
#define NXY   40000      // NXV*NYV
#define NPTS  173184     // BATCH*NCAM*DNUM*FHN*FWN

struct Mats {
    float iR[9];    // inv(post_rots), fp32 LU (gesv-style)
    float comb[9];  // rots @ inv(intrins), fp32 no-FMA matmul
    float tr[3];    // trans
    float pt[3];    // post_trans
};

// fp32 3x3 inverse mimicking numpy's linalg.inv -> LAPACK sgesv (see R1 notes):
// getf2 partial-pivot LU with reciprocal-scaled columns, then unit-lower
// forward solve + reciprocal-multiply backward solve vs identity. No FMA.
__device__ void inv3x3_f32_gesv(const float* __restrict__ Ain, float* __restrict__ inv) {
#pragma clang fp contract(off)
    float A[9];
    for (int k = 0; k < 9; ++k) A[k] = Ain[k];
    int piv[3];
    for (int j = 0; j < 3; ++j) {
        int p = j;
        float amax = fabsf(A[j * 3 + j]);
        for (int i = j + 1; i < 3; ++i) {
            float v = fabsf(A[i * 3 + j]);
            if (v > amax) { amax = v; p = i; }
        }
        piv[j] = p;
        if (p != j)
            for (int k = 0; k < 3; ++k) { float t = A[j*3+k]; A[j*3+k] = A[p*3+k]; A[p*3+k] = t; }
        float rd = 1.0f / A[j * 3 + j];
        for (int i = j + 1; i < 3; ++i) A[i * 3 + j] = A[i * 3 + j] * rd;
        for (int i = j + 1; i < 3; ++i)
            for (int k = j + 1; k < 3; ++k)
                A[i * 3 + k] = A[i * 3 + k] - A[i * 3 + j] * A[j * 3 + k];
    }
    float rdiag[3] = {1.0f / A[0], 1.0f / A[4], 1.0f / A[8]};
    for (int c = 0; c < 3; ++c) {
        float b[3] = {0.0f, 0.0f, 0.0f};
        b[c] = 1.0f;
        for (int j = 0; j < 3; ++j) { int p = piv[j]; if (p != j) { float t = b[j]; b[j] = b[p]; b[p] = t; } }
        for (int k = 0; k < 3; ++k)
            for (int i = k + 1; i < 3; ++i)
                b[i] = b[i] - A[i * 3 + k] * b[k];
        for (int k = 2; k >= 0; --k) {
            b[k] = b[k] * rdiag[k];
            for (int i = 0; i < k; ++i)
                b[i] = b[i] - A[i * 3 + k] * b[k];
        }
        inv[0 + c] = b[0];
        inv[3 + c] = b[1];
        inv[6 + c] = b[2];
    }
}

__global__ void prep_kernel(const float* __restrict__ rots,
                            const float* __restrict__ trans,
                            const float* __restrict__ intrins,
                            const float* __restrict__ post_rots,
                            const float* __restrict__ post_trans,
                            Mats* __restrict__ mats) {
    int i = threadIdx.x;
    if (i >= BATCH * NCAM) return;
    Mats m;
    inv3x3_f32_gesv(post_rots + i * 9, m.iR);
    float invK[9];
    inv3x3_f32_gesv(intrins + i * 9, invK);
    {
#pragma clang fp contract(off)
        for (int r = 0; r < 3; ++r)
            for (int c = 0; c < 3; ++c) {
                float s = rots[i * 9 + r * 3 + 0] * invK[0 * 3 + c];
                s = s + rots[i * 9 + r * 3 + 1] * invK[1 * 3 + c];
                s = s + rots[i * 9 + r * 3 + 2] * invK[2 * 3 + c];
                m.comb[r * 3 + c] = s;
            }
    }
    for (int k = 0; k < 3; ++k) {
        m.tr[k] = trans[i * 3 + k];
        m.pt[k] = post_trans[i * 3 + k];
    }
    mats[i] = m;
}

// Shared geometry: returns voxel flat index (b*NXY + gx*NYV + gy) or -1.
__device__ __forceinline__ int point_voxel(int p, const Mats* __restrict__ mats) {
#pragma clang fp contract(off)
    int w = p % FWN;
    int t = p / FWN;
    int h = t % FHN;
    t /= FHN;
    int d = t % DNUM;
    t /= DNUM;
    int n = t % NCAM;
    int b = t / NCAM;

    const Mats m = mats[b * NCAM + n];

    float u   = (float)((double)w * (351.0 / 21.0)); // linspace(0,351,22)
    float v   = (float)((double)h * (127.0 / 7.0));  // linspace(0,127,8)
    float dep = 4.0f + (float)d;                     // arange(4,45,1)

    float p0 = u - m.pt[0];
    float p1 = v - m.pt[1];
    float p2 = dep - m.pt[2];
    float q0 = m.iR[0] * p0; q0 = q0 + m.iR[1] * p1; q0 = q0 + m.iR[2] * p2;
    float q1 = m.iR[3] * p0; q1 = q1 + m.iR[4] * p1; q1 = q1 + m.iR[5] * p2;
    float q2 = m.iR[6] * p0; q2 = q2 + m.iR[7] * p1; q2 = q2 + m.iR[8] * p2;
    float r0 = q0 * q2;
    float r1 = q1 * q2;
    float e0 = m.comb[0] * r0; e0 = e0 + m.comb[1] * r1; e0 = e0 + m.comb[2] * q2; e0 = e0 + m.tr[0];
    float e1 = m.comb[3] * r0; e1 = e1 + m.comb[4] * r1; e1 = e1 + m.comb[5] * q2; e1 = e1 + m.tr[1];
    float e2 = m.comb[6] * r0; e2 = e2 + m.comb[7] * r1; e2 = e2 + m.comb[8] * q2; e2 = e2 + m.tr[2];

    float gxf = (e0 + 50.0f) / 0.5f;
    float gyf = (e1 + 50.0f) / 0.5f;
    float gzf = (e2 + 10.0f) / 20.0f;
    int gx = (int)gxf;
    int gy = (int)gyf;
    int gz = (int)gzf;
    if (gx < 0 || gx >= NXV || gy < 0 || gy >= NYV || gz < 0 || gz >= 1) return -1;
    return b * NXY + gx * NYV + gy;
}

// Scatter into channel-contiguous workspace vox[b][x][y][c]:
// one point's 128 atomics span 8 contiguous 64B lines (16 lanes/line)
// instead of 128 scattered lines in the out layout.
__global__ __launch_bounds__(128) void scatter_vox_kernel(const float* __restrict__ feats,
                                                          const Mats* __restrict__ mats,
                                                          float* __restrict__ vox) {
    int p = blockIdx.x;
    int vid = point_voxel(p, mats);
    if (vid < 0) return;
    int c = threadIdx.x;
    float f = feats[(size_t)p * CCH + c];
    atomicAdd(vox + (size_t)vid * CCH + c, f);
}

// Transpose vox[b][xy][c] -> out[b][c][xy], LDS 32x32 tiles, coalesced both sides.
__global__ __launch_bounds__(256) void transpose_kernel(const float* __restrict__ vox,
                                                        float* __restrict__ out) {
    __shared__ float tile[32][33];
    int xy0 = blockIdx.x * 32;
    int c0  = blockIdx.y * 32;
    int b   = blockIdx.z;
    int tx = threadIdx.x, ty = threadIdx.y;
    const float* src = vox + (size_t)b * NXY * CCH;
#pragma unroll
    for (int j = 0; j < 32; j += 8)
        tile[ty + j][tx] = src[(size_t)(xy0 + ty + j) * CCH + (c0 + tx)];
    __syncthreads();
    float* dst = out + (size_t)b * CCH * NXY;
#pragma unroll
    for (int j = 0; j < 32; j += 8)
        dst[(size_t)(c0 + ty + j) * NXY + (xy0 + tx)] = tile[tx][ty + j];
}

// Fallback (round-2 path): direct atomic scatter into out layout.
__global__ __launch_bounds__(128) void scatter_direct_kernel(const float* __restrict__ feats,
                                                             const Mats* __restrict__ mats,
                                                             float* __restrict__ out) {
    int p = blockIdx.x;
    int vid = point_voxel(p, mats);
    if (vid < 0) return;
    int b  = vid / NXY;
    int xy = vid % NXY;
    int c = threadIdx.x;
    float f = feats[(size_t)p * CCH + c];
    atomicAdd(out + (size_t)(b * CCH + c) * NXY + xy, f);
}

extern "C" void kernel_launch(void* const* d_in, const int* in_sizes, int n_in,
                              void* d_out, int out_size, void* d_ws, size_t ws_size,
                              hipStream_t stream) {
    const float* cam_feats  = (const float*)d_in[0];
    const float* rots       = (const float*)d_in[1];
    const float* trans      = (const float*)d_in[2];
    const float* intrins    = (const float*)d_in[3];
    const float* post_rots  = (const float*)d_in[4];
    const float* post_trans = (const float*)d_in[5];
    float* out = (float*)d_out;
    Mats* mats = (Mats*)d_ws;

    prep_kernel<<<1, 64, 0, stream>>>(rots, trans, intrins, post_rots, post_trans, mats);

    const size_t vox_off   = 4096;
    const size_t vox_bytes = (size_t)BATCH * NXY * CCH * sizeof(float); // 81.92 MB

    if (ws_size >= vox_off + vox_bytes) {
        float* vox = (float*)((char*)d_ws + vox_off);
        hipMemsetAsync(vox, 0, vox_bytes, stream);
        scatter_vox_kernel<<<NPTS, CCH, 0, stream>>>(cam_feats, mats, vox);
        dim3 grid(NXY / 32, CCH / 32, BATCH);
        dim3 block(32, 8);
        transpose_kernel<<<grid, block, 0, stream>>>(vox, out);
    } else {
        hipMemsetAsync(d_out, 0, (size_t)out_size * sizeof(float), stream);
        scatter_direct_kernel<<<NPTS, CCH, 0, stream>>>(cam_feats, mats, out);
    }
}